// Round 1
// baseline (531.150 us; speedup 1.0000x reference)
//
#include <hip/hip_runtime.h>

#define K_ 4096
#define N_ 4096
#define M_ 8192
#define NOUT_ 128

typedef __bf16 bf16x8 __attribute__((ext_vector_type(8)));
typedef float f32x4 __attribute__((ext_vector_type(4)));
typedef unsigned short ushort8 __attribute__((ext_vector_type(8)));

__device__ __forceinline__ unsigned short f2bf(float f) {
  unsigned u = __builtin_bit_cast(unsigned, f);
  u += 0x7fffu + ((u >> 16) & 1u);   // round-to-nearest-even
  return (unsigned short)(u >> 16);
}

// ---- kernel 1: x fp32 -> bf16 (8 elems/thread) ----
__global__ void cvt_x_kernel(const float4* __restrict__ x4, ushort8* __restrict__ xb) {
  const int t = blockIdx.x * 256 + threadIdx.x;
  float4 a = x4[2 * t];
  float4 b = x4[2 * t + 1];
  ushort8 o;
  o[0] = f2bf(a.x); o[1] = f2bf(a.y); o[2] = f2bf(a.z); o[3] = f2bf(a.w);
  o[4] = f2bf(b.x); o[5] = f2bf(b.y); o[6] = f2bf(b.z); o[7] = f2bf(b.w);
  xb[t] = o;
}

// ---- kernel 2: dequant W + fold outlier weights into last 128 k-columns ----
__global__ void dequant_kernel(const int4* __restrict__ q4,
                               const float* __restrict__ scales,
                               const float* __restrict__ zeros,
                               const float* __restrict__ ow,
                               ushort8* __restrict__ wb) {
  const int t = blockIdx.x * 256 + threadIdx.x;  // N*K/8 threads
  const int n = t >> 9;            // K/8 = 512 chunks per row
  const int k = (t & 511) << 3;
  const int g = k >> 7;            // group = k/128 (8 | 128, aligned)
  const float s = scales[g * N_ + n];
  const float z = zeros[g * N_ + n];
  int4 qa = q4[2 * t], qb = q4[2 * t + 1];
  float f[8];
  f[0] = qa.x * s + z; f[1] = qa.y * s + z; f[2] = qa.z * s + z; f[3] = qa.w * s + z;
  f[4] = qb.x * s + z; f[5] = qb.y * s + z; f[6] = qb.z * s + z; f[7] = qb.w * s + z;
  if (k >= K_ - NOUT_) {
    const float4* o4 = (const float4*)(ow + n * NOUT_ + (k - (K_ - NOUT_)));
    float4 oa = o4[0], ob = o4[1];
    f[0] += oa.x; f[1] += oa.y; f[2] += oa.z; f[3] += oa.w;
    f[4] += ob.x; f[5] += ob.y; f[6] += ob.z; f[7] += ob.w;
  }
  ushort8 r;
  #pragma unroll
  for (int i = 0; i < 8; ++i) r[i] = f2bf(f[i]);
  wb[t] = r;
}

// ---- kernel 3: 128x128 tile bf16 MFMA GEMM, y = x*W'^T + bias ----
// 4 waves (2x2), each 64x64; BK=64; global_load_lds width-16 staging;
// XOR chunk swizzle (chunk c of row r stored at slot c^(r&7)) applied to the
// global SOURCE address at staging time (LDS dest is wave-uniform + lane*16,
// so the LDS side must stay linear) and to the ds_read address at use time.
__global__ __launch_bounds__(256, 3) void gemm_kernel(
    const unsigned short* __restrict__ xb,
    const unsigned short* __restrict__ wb,
    const float* __restrict__ bias,
    float* __restrict__ out) {
  __shared__ char sA[16384];   // 128 rows x 64 bf16 (128 B/row)
  __shared__ char sB[16384];

  const int tid  = threadIdx.x;
  const int w    = tid >> 6;
  const int lane = tid & 63;
  const int q    = lane >> 4;
  const int l16  = lane & 15;
  const int x7   = l16 & 7;
  const int wr   = w >> 1;
  const int wc   = w & 1;

  const int m0 = blockIdx.y * 128;
  const int n0 = blockIdx.x * 128;

  const unsigned short* gA[4];
  const unsigned short* gB[4];
  char* ldsA[4];
  char* ldsB[4];
  #pragma unroll
  for (int i = 0; i < 4; ++i) {
    const int o  = i * 4096 + w * 1024 + lane * 16;  // linear byte offset in tile
    const int r  = o >> 7;                           // row (128 B rows)
    const int cs = (o >> 4) & 7;                     // LDS slot this lane fills
    const int cg = cs ^ (r & 7);                     // global chunk that belongs there
    gA[i] = xb + (size_t)(m0 + r) * K_ + cg * 8;
    gB[i] = wb + (size_t)(n0 + r) * K_ + cg * 8;
    ldsA[i] = sA + i * 4096 + w * 1024;              // wave-uniform LDS base
    ldsB[i] = sB + i * 4096 + w * 1024;
  }

  const char* pA = sA + (wr * 64 + l16) * 128;
  const char* pB = sB + (wc * 64 + l16) * 128;
  const int slot0 = ((0 + q) ^ x7) * 16;   // k-step 0: chunks 0..3
  const int slot1 = ((4 + q) ^ x7) * 16;   // k-step 1: chunks 4..7

  f32x4 acc[4][4] = {};

  for (int kt = 0; kt < K_ / 64; ++kt) {
    const int kof = kt * 64;
    #pragma unroll
    for (int i = 0; i < 4; ++i)
      __builtin_amdgcn_global_load_lds(
          (__attribute__((address_space(1))) void*)(gA[i] + kof),
          (__attribute__((address_space(3))) void*)ldsA[i], 16, 0, 0);
    #pragma unroll
    for (int i = 0; i < 4; ++i)
      __builtin_amdgcn_global_load_lds(
          (__attribute__((address_space(1))) void*)(gB[i] + kof),
          (__attribute__((address_space(3))) void*)ldsB[i], 16, 0, 0);
    __syncthreads();

    #pragma unroll
    for (int s = 0; s < 2; ++s) {
      const int slot = s ? slot1 : slot0;
      bf16x8 a[4], b[4];
      #pragma unroll
      for (int i = 0; i < 4; ++i)
        a[i] = *(const bf16x8*)(pA + i * 2048 + slot);
      #pragma unroll
      for (int j = 0; j < 4; ++j)
        b[j] = *(const bf16x8*)(pB + j * 2048 + slot);
      #pragma unroll
      for (int i = 0; i < 4; ++i)
        #pragma unroll
        for (int j = 0; j < 4; ++j)
          acc[i][j] = __builtin_amdgcn_mfma_f32_16x16x32_bf16(a[i], b[j], acc[i][j], 0, 0, 0);
    }
    __syncthreads();
  }

  float bv[4];
  #pragma unroll
  for (int j = 0; j < 4; ++j)
    bv[j] = bias[n0 + wc * 64 + j * 16 + l16];

  // C/D layout: col = lane&15, row = (lane>>4)*4 + reg  [m89/m91 verified]
  #pragma unroll
  for (int i = 0; i < 4; ++i) {
    const int mrow = m0 + wr * 64 + i * 16 + q * 4;
    #pragma unroll
    for (int j = 0; j < 4; ++j) {
      const int n = n0 + wc * 64 + j * 16 + l16;
      float* op = out + (size_t)mrow * N_ + n;
      #pragma unroll
      for (int r = 0; r < 4; ++r)
        op[(size_t)r * N_] = acc[i][j][r] + bv[j];
    }
  }
}

extern "C" void kernel_launch(void* const* d_in, const int* in_sizes, int n_in,
                              void* d_out, int out_size, void* d_ws, size_t ws_size,
                              hipStream_t stream) {
  const float* x      = (const float*)d_in[0];
  const int*   qw     = (const int*)d_in[1];
  const float* scales = (const float*)d_in[2];
  const float* zeros  = (const float*)d_in[3];
  const float* ow     = (const float*)d_in[4];
  const float* bias   = (const float*)d_in[5];
  float* out = (float*)d_out;

  unsigned short* xb = (unsigned short*)d_ws;            // 64 MiB
  unsigned short* wb = xb + (size_t)M_ * K_;             // +32 MiB

  cvt_x_kernel<<<(M_ * K_ / 8) / 256, 256, 0, stream>>>((const float4*)x, (ushort8*)xb);
  dequant_kernel<<<(N_ * K_ / 8) / 256, 256, 0, stream>>>((const int4*)qw, scales, zeros, ow,
                                                          (ushort8*)wb);
  dim3 grid(N_ / 128, M_ / 128);
  gemm_kernel<<<grid, 256, 0, stream>>>(xb, wb, bias, out);
}